// Round 7
// baseline (87.567 us; speedup 1.0000x reference)
//
#include <hip/hip_runtime.h>
#include <hip/hip_bf16.h>
#include <math.h>

#define B_ 128
#define C_ 8
#define T_ 128
#define K_ 20
#define S_ 128

#define XROW 388            // cc x row stride: %4==0 (float4), %32==4 (groups de-alias)
#define BTROW 132
#define SWZ(j) ((j) ^ ((((j) >> 5) & 7) << 2))
#define XP_GUARD 16
#define BT_BASE (4 * XROW + XP_GUARD)   // 1568 floats
#define SMEMF 3680          // floats: cc 1568 + 4*528 = 3680 (dtw path uses none)

template <int CTRL, int RMASK>
__device__ __forceinline__ float dppf(float oldv, float v) {
    return __int_as_float(__builtin_amdgcn_update_dpp(
        __float_as_int(oldv), __float_as_int(v), CTRL, RMASK, 0xf, false));
}

__device__ __forceinline__ float rdlane(float v, int l) {
    return __int_as_float(__builtin_amdgcn_readlane(__float_as_int(v), l));
}

// 1920 blocks x 256 threads. u%3==0 -> DTW (4 waves, one pair/wave, row-sweep
// min-plus scan, ALL-REGISTER inner loop). Else -> CC (4 waves share one
// (b,half) x-tile; each wave one k: 4 channels x 16 lanes x 16 lags).
__global__ __launch_bounds__(256) void fused_kernel(const float* __restrict__ x,
                                                    const float* __restrict__ bary,
                                                    const float* __restrict__ top_dist,
                                                    const float* __restrict__ bottom_cc,
                                                    int* __restrict__ dtw_gt,
                                                    int* __restrict__ cc_fail2) {
    __shared__ __align__(16) float smem[SMEMF];
    const float INF = __builtin_inff();
    int u = blockIdx.x;
    int tid = threadIdx.x;
    int w = tid >> 6;
    int lane = tid & 63;

    if (u % 3 == 0) {
        // ------------------------------ DTW ------------------------------
        // Lane owns cols s0=2*lane, s1=2*lane+1 (barycenter regs, fixed) and
        // rows 2*lane, 2*lane+1 of x (broadcast per row via v_readlane).
        int pg = u / 3;                  // 0..639
        int b  = pg / 5;
        int kg = pg - b * 5;
        int kk = kg * 4 + w;             // 0..19

        // x rows in registers: lane l holds x[b][c][2l], x[b][c][2l+1].
        float xr0[8], xr1[8];
        {
            const float* xb = x + (size_t)b * (C_ * T_);
            #pragma unroll
            for (int c = 0; c < 8; ++c) {
                float2 v = *(const float2*)(xb + c * T_ + 2 * lane);  // coalesced 8B
                xr0[c] = v.x;
                xr1[c] = v.y;
            }
        }
        float X20 = 0.f, X21 = 0.f;
        #pragma unroll
        for (int c = 0; c < 8; ++c) {
            X20 = fmaf(xr0[c], xr0[c], X20);
            X21 = fmaf(xr1[c], xr1[c], X21);
        }

        // Barycenter cols: -2*b and B2 in registers.
        float bv0[8], bv1[8], B20, B21;
        {
            const float4* bp = (const float4*)(bary + ((size_t)kk * S_ + 2 * lane) * C_);
            float4 q0 = bp[0], q1 = bp[1], q2 = bp[2], q3 = bp[3];
            bv0[0]=q0.x; bv0[1]=q0.y; bv0[2]=q0.z; bv0[3]=q0.w;
            bv0[4]=q1.x; bv0[5]=q1.y; bv0[6]=q1.z; bv0[7]=q1.w;
            bv1[0]=q2.x; bv1[1]=q2.y; bv1[2]=q2.z; bv1[3]=q2.w;
            bv1[4]=q3.x; bv1[5]=q3.y; bv1[6]=q3.z; bv1[7]=q3.w;
            float s0 = 0.f, s1 = 0.f;
            #pragma unroll
            for (int ch = 0; ch < 8; ++ch) {
                s0 = fmaf(bv0[ch], bv0[ch], s0);
                s1 = fmaf(bv1[ch], bv1[ch], s1);
            }
            B20 = s0; B21 = s1;
            #pragma unroll
            for (int ch = 0; ch < 8; ++ch) { bv0[ch] *= -2.f; bv1[ch] *= -2.f; }
        }

        float n0 = INF, n1 = INF;                  // previous-row D values
        float dfix = (lane == 0) ? 0.f : INF;      // virtual D[-1][-1]=0, row 0 only

        // Per row: n[s] = cst[s] + min(min(up,diag), n[s-1]) via min-plus scan.
        auto dprow = [&](const float (&xr)[8], float X2v, int tp) {
            float X2t = rdlane(X2v, tp);
            float a0 = X2t + B20, a1 = X2t + B21;
            #pragma unroll
            for (int ch = 0; ch < 8; ++ch) {
                float xs = rdlane(xr[ch], tp);
                a0 = fmaf(bv0[ch], xs, a0);
                a1 = fmaf(bv1[ch], xs, a1);
            }
            a0 = fmaxf(a0, 0.f);
            a1 = fmaxf(a1, 0.f);

            float diag = dppf<0x138, 0xf>(INF, n1);   // wave_shr:1, lane0 -> INF
            float m0 = fminf(fminf(n0, diag), dfix);
            float m1 = fminf(n1, n0);
            dfix = INF;
            float C0 = a0 + m0;
            float C1 = a1 + m1;
            float C  = fminf(C1, C0 + a1);   // in-lane compose (col0 then col1)
            float A  = a0 + a1;

            // 64-lane inclusive min-plus scan (identity = (INF, 0) via dpp-old).
            float Ci, Ai;
            Ci = dppf<0x111, 0xf>(INF, C); Ai = dppf<0x111, 0xf>(0.f, A);
            C = fminf(C, Ci + A); A = A + Ai;
            Ci = dppf<0x112, 0xf>(INF, C); Ai = dppf<0x112, 0xf>(0.f, A);
            C = fminf(C, Ci + A); A = A + Ai;
            Ci = dppf<0x114, 0xf>(INF, C); Ai = dppf<0x114, 0xf>(0.f, A);
            C = fminf(C, Ci + A); A = A + Ai;
            Ci = dppf<0x118, 0xf>(INF, C); Ai = dppf<0x118, 0xf>(0.f, A);
            C = fminf(C, Ci + A); A = A + Ai;
            Ci = dppf<0x142, 0xa>(INF, C); Ai = dppf<0x142, 0xa>(0.f, A);  // bcast15 -> rows 1,3
            C = fminf(C, Ci + A); A = A + Ai;
            Ci = dppf<0x143, 0xc>(INF, C); Ai = dppf<0x143, 0xc>(0.f, A);  // bcast31 -> rows 2,3
            C = fminf(C, Ci + A); A = A + Ai;

            float Cp = dppf<0x138, 0xf>(INF, C);      // exclusive (prev-lane incl)
            n0 = fminf(C0, Cp + a0);
            n1 = C;
        };

        #pragma unroll 2
        for (int tp = 0; tp < 64; ++tp) {
            dprow(xr0, X20, tp);   // row 2*tp
            dprow(xr1, X21, tp);   // row 2*tp+1
        }

        if (lane == 63)
            dtw_gt[b * K_ + kk] = (logf(n1) > top_dist[kk]) ? 1 : 0;
    } else {
        // ------------------------------ CC -------------------------------
        int cb = u - u / 3 - 1;          // 0..1279
        int bh = cb / 5;                 // (b, half)
        int g5 = cb - bh * 5;
        int b  = bh >> 1;
        int h  = bh & 1;
        int kk = g5 * 4 + w;             // 0..19
        int cbase = h * 4;

        float* xp = smem;                         // 4 x XROW (+guard), swizzled
        float* bt = smem + BT_BASE + w * (4 * BTROW);

        const float* xsrc = x + ((size_t)b * C_ + cbase) * T_;
        #pragma unroll
        for (int c = 0; c < 4; ++c) {
            for (int j = tid; j < XROW; j += 256) {
                int t = j - (S_ - 1);
                float v = (t >= 0 && t < T_) ? xsrc[c * T_ + t] : 0.f;
                xp[c * XROW + SWZ(j)] = v;
            }
        }
        #pragma unroll
        for (int r = 0; r < 2; ++r) {
            int s = r * 64 + lane;
            float4 q = *(const float4*)(bary + ((size_t)kk * S_ + s) * C_ + cbase);
            bt[0 * BTROW + s] = q.x;
            bt[1 * BTROW + s] = q.y;
            bt[2 * BTROW + s] = q.z;
            bt[3 * BTROW + s] = q.w;
        }
        __syncthreads();

        int cl = lane >> 4;
        int gl = lane & 15;
        int lag0 = gl << 4;              // 16 lags/lane
        const float* xr = xp + cl * XROW;
        const float* br = bt + cl * BTROW;

        float wdw[20];
        #pragma unroll
        for (int i = 0; i < 5; ++i) {
            float4 v = *(const float4*)&xr[SWZ(lag0 + i * 4)];
            wdw[i * 4 + 0] = v.x; wdw[i * 4 + 1] = v.y;
            wdw[i * 4 + 2] = v.z; wdw[i * 4 + 3] = v.w;
        }
        float acc[16];
        #pragma unroll
        for (int j = 0; j < 16; ++j) acc[j] = 0.f;

        #pragma unroll
        for (int s4 = 0; s4 < S_; s4 += 4) {    // FULL unroll: window movs vanish
            float4 bq = *(const float4*)&br[s4];
            float bvals[4] = {bq.x, bq.y, bq.z, bq.w};
            #pragma unroll
            for (int uu = 0; uu < 4; ++uu) {
                #pragma unroll
                for (int j = 0; j < 16; ++j)
                    acc[j] = fmaf(wdw[uu + j], bvals[uu], acc[j]);
            }
            #pragma unroll
            for (int i = 0; i < 16; ++i) wdw[i] = wdw[i + 4];
            float4 v = *(const float4*)&xr[SWZ(lag0 + s4 + 20)];  // last iter: unused, in-bounds
            wdw[16] = v.x; wdw[17] = v.y; wdw[18] = v.z; wdw[19] = v.w;
        }

        if (gl == 15) acc[15] = -INF;    // lag 255 doesn't exist
        float m = acc[0];
        #pragma unroll
        for (int j = 1; j < 16; ++j) m = fmaxf(m, acc[j]);
        #pragma unroll
        for (int off = 8; off >= 1; off >>= 1)
            m = fmaxf(m, __shfl_xor(m, off));

        bool fail = false;
        if (gl == 0) fail = (m <= bottom_cc[kk * C_ + cbase + cl]);
        unsigned long long bal = __ballot(fail);
        if (lane == 0) cc_fail2[(b * K_ + kk) * 2 + h] = (bal != 0ULL) ? 1 : 0;
    }
}

__global__ void final_kernel(const int* __restrict__ preds,
                             const int* __restrict__ dtw_gt,
                             const int* __restrict__ cc_fail2,
                             int* __restrict__ out) {
    int b = threadIdx.x;
    if (b < B_) {
        int dtw_all = 1, cc_all = 1;
        #pragma unroll
        for (int k = 0; k < K_; ++k) {
            dtw_all &= dtw_gt[b * K_ + k];
            cc_all &= (cc_fail2[(b * K_ + k) * 2] | cc_fail2[(b * K_ + k) * 2 + 1]);
        }
        out[b] = (dtw_all | cc_all) ? K_ : preds[b];
    }
}

extern "C" void kernel_launch(void* const* d_in, const int* in_sizes, int n_in,
                              void* d_out, int out_size, void* d_ws, size_t ws_size,
                              hipStream_t stream) {
    const float* x         = (const float*)d_in[0];  // [B, C, T]
    const int*   preds     = (const int*)d_in[1];    // [B]
    const float* bary      = (const float*)d_in[2];  // [K, S, C]
    const float* top_dist  = (const float*)d_in[3];  // [K]
    const float* bottom_cc = (const float*)d_in[4];  // [K, C]
    int* out = (int*)d_out;                          // [B] int32

    int* dtw_gt   = (int*)d_ws;                // [B*K]
    int* cc_fail2 = dtw_gt + B_ * K_;          // [B*K*2]

    fused_kernel<<<1920, 256, 0, stream>>>(x, bary, top_dist, bottom_cc, dtw_gt, cc_fail2);
    final_kernel<<<1, 128, 0, stream>>>(preds, dtw_gt, cc_fail2, out);
}

// Round 8
// 72.428 us; speedup vs baseline: 1.2090x; 1.2090x over previous
//
#include <hip/hip_runtime.h>
#include <hip/hip_bf16.h>
#include <math.h>

#define B_ 128
#define C_ 8
#define T_ 128
#define K_ 20
#define S_ 128

#define XROW 388            // cc x row stride: %4==0 (float4), %32==4 (groups de-alias)
#define BTROW 132
#define SWZ(j) ((j) ^ ((((j) >> 5) & 7) << 2))
#define XP_GUARD 16
#define BT_BASE (4 * XROW + XP_GUARD)   // 1568 floats
#define SMEMF 3680          // floats: dtw tile 1536; cc 1568 + 4*528 = 3680

template <int CTRL, int RMASK>
__device__ __forceinline__ float dppf(float oldv, float v) {
    return __int_as_float(__builtin_amdgcn_update_dpp(
        __float_as_int(oldv), __float_as_int(v), CTRL, RMASK, 0xf, false));
}

// 1920 blocks x 256 threads. u%3==0 -> DTW (4 waves, one pair/wave, row-sweep
// min-plus scan, prefetch-pipelined LDS broadcast reads). Else -> CC (4 waves
// share one (b,half) x-tile; each wave one k: 4 ch x 16 lanes x 16 lags).
__global__ __launch_bounds__(256) void fused_kernel(const float* __restrict__ x,
                                                    const float* __restrict__ bary,
                                                    const float* __restrict__ top_dist,
                                                    const float* __restrict__ bottom_cc,
                                                    int* __restrict__ dtw_gt,
                                                    int* __restrict__ cc_fail2) {
    __shared__ __align__(16) float smem[SMEMF];
    const float INF = __builtin_inff();
    int u = blockIdx.x;
    int tid = threadIdx.x;
    int w = tid >> 6;
    int lane = tid & 63;

    if (u % 3 == 0) {
        // ------------------------------ DTW ------------------------------
        // Row-sweep DP, lane owns cols s0=2*lane, s1=2*lane+1. Per row:
        // n[s] = cst[s] + min(min(up,diag), n[s-1]) via min-plus affine scan.
        int pg = u / 3;                  // 0..639
        int b  = pg / 5;
        int kg = pg - b * 5;
        int kk = kg * 4 + w;             // 0..19
        float* tile = smem;              // [128][12]: x[t][c] + X2 at col 8

        {   // transpose-stage x[b]: [c][t] -> tile[t*12+c]
            int c  = tid >> 5;
            int t0 = (tid & 31) * 4;
            float4 v = *(const float4*)(x + ((size_t)b * C_ + c) * T_ + t0);
            tile[(t0 + 0) * 12 + c] = v.x;
            tile[(t0 + 1) * 12 + c] = v.y;
            tile[(t0 + 2) * 12 + c] = v.z;
            tile[(t0 + 3) * 12 + c] = v.w;
        }
        __syncthreads();
        if (tid < T_) {                  // X2[t] -> tile[t*12+8]
            const float* rp = tile + tid * 12;
            float4 xa = *(const float4*)rp;
            float4 xh = *(const float4*)(rp + 4);
            float s = xa.x * xa.x;
            s = fmaf(xa.y, xa.y, s); s = fmaf(xa.z, xa.z, s); s = fmaf(xa.w, xa.w, s);
            s = fmaf(xh.x, xh.x, s); s = fmaf(xh.y, xh.y, s); s = fmaf(xh.z, xh.z, s);
            s = fmaf(xh.w, xh.w, s);
            tile[tid * 12 + 8] = s;
        }
        __syncthreads();

        // Barycenter cols: -2*b and B2 in registers (lane-fixed).
        float bv0[8], bv1[8], B20, B21;
        {
            const float4* bp = (const float4*)(bary + ((size_t)kk * S_ + 2 * lane) * C_);
            float4 q0 = bp[0], q1 = bp[1], q2 = bp[2], q3 = bp[3];
            bv0[0]=q0.x; bv0[1]=q0.y; bv0[2]=q0.z; bv0[3]=q0.w;
            bv0[4]=q1.x; bv0[5]=q1.y; bv0[6]=q1.z; bv0[7]=q1.w;
            bv1[0]=q2.x; bv1[1]=q2.y; bv1[2]=q2.z; bv1[3]=q2.w;
            bv1[4]=q3.x; bv1[5]=q3.y; bv1[6]=q3.z; bv1[7]=q3.w;
            float s0 = 0.f, s1 = 0.f;
            #pragma unroll
            for (int ch = 0; ch < 8; ++ch) {
                s0 = fmaf(bv0[ch], bv0[ch], s0);
                s1 = fmaf(bv1[ch], bv1[ch], s1);
            }
            B20 = s0; B21 = s1;
            #pragma unroll
            for (int ch = 0; ch < 8; ++ch) { bv0[ch] *= -2.f; bv1[ch] *= -2.f; }
        }

        float n0 = INF, n1 = INF;                  // previous-row D values
        float dfix = (lane == 0) ? 0.f : INF;      // virtual D[-1][-1]=0, row 0 only

        __builtin_amdgcn_s_setprio(1);
        // Prefetch row 0 (uniform-address broadcast reads: conflict-free).
        float4 xa_n = *(const float4*)tile;
        float4 xh_n = *(const float4*)(tile + 4);
        float x2_n  = tile[8];

        #pragma unroll 2
        for (int t = 0; t < T_; ++t) {
            float4 xa = xa_n, xh = xh_n;
            float X2t = x2_n;
            // Prefetch row t+1 (wraps to row 0 on last iter; unused).
            const float* rpn = tile + ((t + 1) & (T_ - 1)) * 12;
            xa_n = *(const float4*)rpn;
            xh_n = *(const float4*)(rpn + 4);
            x2_n = rpn[8];

            float xv[8];
            xv[0]=xa.x; xv[1]=xa.y; xv[2]=xa.z; xv[3]=xa.w;
            xv[4]=xh.x; xv[5]=xh.y; xv[6]=xh.z; xv[7]=xh.w;
            float a0 = X2t + B20, a1 = X2t + B21;
            #pragma unroll
            for (int ch = 0; ch < 8; ++ch) {
                a0 = fmaf(bv0[ch], xv[ch], a0);
                a1 = fmaf(bv1[ch], xv[ch], a1);
            }
            a0 = fmaxf(a0, 0.f);
            a1 = fmaxf(a1, 0.f);

            float diag = dppf<0x138, 0xf>(INF, n1);   // wave_shr:1, lane0 -> INF
            float m0 = fminf(fminf(n0, diag), dfix);
            float m1 = fminf(n1, n0);
            dfix = INF;
            float C0 = a0 + m0;
            float C1 = a1 + m1;
            float C  = fminf(C1, C0 + a1);   // in-lane compose (col0 then col1)
            float A  = a0 + a1;

            // 64-lane inclusive min-plus scan (identity = (INF,0) via dpp-old).
            float Ci, Ai;
            Ci = dppf<0x111, 0xf>(INF, C); Ai = dppf<0x111, 0xf>(0.f, A);
            C = fminf(C, Ci + A); A = A + Ai;
            Ci = dppf<0x112, 0xf>(INF, C); Ai = dppf<0x112, 0xf>(0.f, A);
            C = fminf(C, Ci + A); A = A + Ai;
            Ci = dppf<0x114, 0xf>(INF, C); Ai = dppf<0x114, 0xf>(0.f, A);
            C = fminf(C, Ci + A); A = A + Ai;
            Ci = dppf<0x118, 0xf>(INF, C); Ai = dppf<0x118, 0xf>(0.f, A);
            C = fminf(C, Ci + A); A = A + Ai;
            Ci = dppf<0x142, 0xa>(INF, C); Ai = dppf<0x142, 0xa>(0.f, A);  // bcast15
            C = fminf(C, Ci + A); A = A + Ai;
            Ci = dppf<0x143, 0xc>(INF, C); Ai = dppf<0x143, 0xc>(0.f, A);  // bcast31
            C = fminf(C, Ci + A); A = A + Ai;

            float Cp = dppf<0x138, 0xf>(INF, C);      // exclusive (prev-lane incl)
            n0 = fminf(C0, Cp + a0);
            n1 = C;
        }
        __builtin_amdgcn_s_setprio(0);

        if (lane == 63)
            dtw_gt[b * K_ + kk] = (logf(n1) > top_dist[kk]) ? 1 : 0;
    } else {
        // ------------------------------ CC -------------------------------
        int cb = u - u / 3 - 1;          // 0..1279
        int bh = cb / 5;                 // (b, half)
        int g5 = cb - bh * 5;
        int b  = bh >> 1;
        int h  = bh & 1;
        int kk = g5 * 4 + w;             // 0..19
        int cbase = h * 4;

        float* xp = smem;                         // 4 x XROW (+guard), swizzled
        float* bt = smem + BT_BASE + w * (4 * BTROW);

        const float* xsrc = x + ((size_t)b * C_ + cbase) * T_;
        #pragma unroll
        for (int c = 0; c < 4; ++c) {
            for (int j = tid; j < XROW; j += 256) {
                int t = j - (S_ - 1);
                float v = (t >= 0 && t < T_) ? xsrc[c * T_ + t] : 0.f;
                xp[c * XROW + SWZ(j)] = v;
            }
        }
        #pragma unroll
        for (int r = 0; r < 2; ++r) {
            int s = r * 64 + lane;
            float4 q = *(const float4*)(bary + ((size_t)kk * S_ + s) * C_ + cbase);
            bt[0 * BTROW + s] = q.x;
            bt[1 * BTROW + s] = q.y;
            bt[2 * BTROW + s] = q.z;
            bt[3 * BTROW + s] = q.w;
        }
        __syncthreads();

        int cl = lane >> 4;
        int gl = lane & 15;
        int lag0 = gl << 4;              // 16 lags/lane
        const float* xr = xp + cl * XROW;
        const float* br = bt + cl * BTROW;

        float wdw[20];
        #pragma unroll
        for (int i = 0; i < 5; ++i) {
            float4 v = *(const float4*)&xr[SWZ(lag0 + i * 4)];
            wdw[i * 4 + 0] = v.x; wdw[i * 4 + 1] = v.y;
            wdw[i * 4 + 2] = v.z; wdw[i * 4 + 3] = v.w;
        }
        float acc[16];
        #pragma unroll
        for (int j = 0; j < 16; ++j) acc[j] = 0.f;

        #pragma unroll 8
        for (int s4 = 0; s4 < S_; s4 += 4) {
            float4 bq = *(const float4*)&br[s4];
            float bvals[4] = {bq.x, bq.y, bq.z, bq.w};
            #pragma unroll
            for (int uu = 0; uu < 4; ++uu) {
                #pragma unroll
                for (int j = 0; j < 16; ++j)
                    acc[j] = fmaf(wdw[uu + j], bvals[uu], acc[j]);
            }
            #pragma unroll
            for (int i = 0; i < 16; ++i) wdw[i] = wdw[i + 4];
            float4 v = *(const float4*)&xr[SWZ(lag0 + s4 + 20)];  // last iter: unused, in-bounds
            wdw[16] = v.x; wdw[17] = v.y; wdw[18] = v.z; wdw[19] = v.w;
        }

        if (gl == 15) acc[15] = -INF;    // lag 255 doesn't exist
        float m = acc[0];
        #pragma unroll
        for (int j = 1; j < 16; ++j) m = fmaxf(m, acc[j]);
        #pragma unroll
        for (int off = 8; off >= 1; off >>= 1)
            m = fmaxf(m, __shfl_xor(m, off));

        bool fail = false;
        if (gl == 0) fail = (m <= bottom_cc[kk * C_ + cbase + cl]);
        unsigned long long bal = __ballot(fail);
        if (lane == 0) cc_fail2[(b * K_ + kk) * 2 + h] = (bal != 0ULL) ? 1 : 0;
    }
}

__global__ void final_kernel(const int* __restrict__ preds,
                             const int* __restrict__ dtw_gt,
                             const int* __restrict__ cc_fail2,
                             int* __restrict__ out) {
    int b = threadIdx.x;
    if (b < B_) {
        int dtw_all = 1, cc_all = 1;
        #pragma unroll
        for (int k = 0; k < K_; ++k) {
            dtw_all &= dtw_gt[b * K_ + k];
            cc_all &= (cc_fail2[(b * K_ + k) * 2] | cc_fail2[(b * K_ + k) * 2 + 1]);
        }
        out[b] = (dtw_all | cc_all) ? K_ : preds[b];
    }
}

extern "C" void kernel_launch(void* const* d_in, const int* in_sizes, int n_in,
                              void* d_out, int out_size, void* d_ws, size_t ws_size,
                              hipStream_t stream) {
    const float* x         = (const float*)d_in[0];  // [B, C, T]
    const int*   preds     = (const int*)d_in[1];    // [B]
    const float* bary      = (const float*)d_in[2];  // [K, S, C]
    const float* top_dist  = (const float*)d_in[3];  // [K]
    const float* bottom_cc = (const float*)d_in[4];  // [K, C]
    int* out = (int*)d_out;                          // [B] int32

    int* dtw_gt   = (int*)d_ws;                // [B*K]
    int* cc_fail2 = dtw_gt + B_ * K_;          // [B*K*2]

    fused_kernel<<<1920, 256, 0, stream>>>(x, bary, top_dist, bottom_cc, dtw_gt, cc_fail2);
    final_kernel<<<1, 128, 0, stream>>>(preds, dtw_gt, cc_fail2, out);
}